// Round 2
// baseline (52.631 us; speedup 1.0000x reference)
//
#include <hip/hip_runtime.h>
#include <hip/hip_bf16.h>

typedef __attribute__((ext_vector_type(8))) short bf16x8;   // 8 bf16 (4 VGPRs)
typedef __attribute__((ext_vector_type(4))) float f32x4;    // MFMA accumulator

#define CA_EPS 1e-6f

__device__ __forceinline__ unsigned short f2bf(float f) {
  // round-to-nearest-even bf16
  unsigned u = __float_as_uint(f);
  u += 0x7fffu + ((u >> 16) & 1u);
  return (unsigned short)(u >> 16);
}

// Gate + L2-normalize each 128-float row, emit bf16. One launch covers both
// X (blocks [0, rowsX/8)) and Y (blocks above) -- 8 rows per 256-thread block,
// so the X/Y split is block-uniform (no divergence).
__global__ void __launch_bounds__(256) gate_norm_kernel(
    const float* __restrict__ X, const float* __restrict__ A1,
    const float* __restrict__ Y, const float* __restrict__ A2,
    unsigned short* __restrict__ outX, unsigned short* __restrict__ outY,
    int rowsX) {
  int row = (int)((blockIdx.x * 256 + threadIdx.x) >> 5);
  int l = threadIdx.x & 31;
  const float* src;
  const float* gate;
  unsigned short* dst;
  if (row < rowsX) {
    src = X; gate = A1; dst = outX;
  } else {
    src = Y; gate = A2; dst = outY; row -= rowsX;
  }
  const float4 x = *(const float4*)(src + (size_t)row * 128 + l * 4);
  const float4 a = *(const float4*)(gate + (size_t)row * 128 + l * 4);
  float g0 = x.x * a.x, g1 = x.y * a.y, g2 = x.z * a.z, g3 = x.w * a.w;
  float ss = g0 * g0 + g1 * g1 + g2 * g2 + g3 * g3;
#pragma unroll
  for (int off = 16; off; off >>= 1) ss += __shfl_xor(ss, off);
  float inv = 1.0f / sqrtf(fmaxf(ss, CA_EPS));
  ushort4 o;
  o.x = f2bf(g0 * inv);
  o.y = f2bf(g1 * inv);
  o.z = f2bf(g2 * inv);
  o.w = f2bf(g3 * inv);
  *(ushort4*)(dst + (size_t)row * 128 + l * 4) = o;
}

// C[b][n][m] = sum_k Xn[b][n][k] * Yn[b][m][k]  (bf16 operands, K=128 = whole row)
// No LDS: each lane gathers its MFMA fragment (16 B of a row) directly from
// L2/L3-resident operands. 128x128 output tile, 4 waves, acc[4][4] per wave.
// C stores are nontemporal (write-once) to protect operand L2 residency.
__global__ void __launch_bounds__(256) cosine_gemm_kernel(
    const unsigned short* __restrict__ Xn,  // (B, 2048, 128) bf16
    const unsigned short* __restrict__ Yn,  // (B, 2048, 128) bf16
    float* __restrict__ C) {                // (B, 2048, 2048) f32
  const int tid = threadIdx.x;
  const int lane = tid & 63;
  const int w = tid >> 6;  // wave 0..3
  const int wr = w >> 1;   // wave row (0..1): 64-row slab of X tile
  const int wc = w & 1;    // wave col (0..1): 64-row slab of Y tile

  const int tn = blockIdx.x;
  const int tm = blockIdx.y;
  const int b = blockIdx.z;

  const int r16 = lane & 15;  // frag row (A) / frag col (B,C)
  const int kq = lane >> 4;   // k-quarter 0..3

  // Fragment base rows for this lane (row-major, 128 bf16 = 256 B per row).
  const unsigned short* Arow =
      Xn + ((size_t)b * 2048 + (size_t)tn * 128 + wr * 64 + r16) * 128;
  const unsigned short* Brow =
      Yn + ((size_t)b * 2048 + (size_t)tm * 128 + wc * 64 + r16) * 128;

  f32x4 acc[4][4] = {};
#pragma unroll
  for (int kk = 0; kk < 4; ++kk) {
    const int kc = kk * 4 + kq;  // 8-element K-chunk (0..15)
    bf16x8 af[4], bfr[4];
#pragma unroll
    for (int mi = 0; mi < 4; ++mi)
      af[mi] = *(const bf16x8*)(Arow + (size_t)mi * 16 * 128 + kc * 8);
#pragma unroll
    for (int ni = 0; ni < 4; ++ni)
      bfr[ni] = *(const bf16x8*)(Brow + (size_t)ni * 16 * 128 + kc * 8);
#pragma unroll
    for (int mi = 0; mi < 4; ++mi)
#pragma unroll
      for (int ni = 0; ni < 4; ++ni)
        acc[mi][ni] = __builtin_amdgcn_mfma_f32_16x16x32_bf16(
            af[mi], bfr[ni], acc[mi][ni], 0, 0, 0);
  }

  // C/D layout (m89-verified): col = lane&15, row = (lane>>4)*4 + reg.
  float* Cb = C + ((size_t)b * 2048 + (size_t)tn * 128 + wr * 64) * 2048 +
              (size_t)tm * 128 + wc * 64;
#pragma unroll
  for (int mi = 0; mi < 4; ++mi) {
#pragma unroll
    for (int j = 0; j < 4; ++j) {
      float* crow = Cb + (size_t)(mi * 16 + kq * 4 + j) * 2048 + r16;
#pragma unroll
      for (int ni = 0; ni < 4; ++ni)
        __builtin_nontemporal_store(acc[mi][ni][j], crow + ni * 16);
    }
  }
}

extern "C" void kernel_launch(void* const* d_in, const int* in_sizes, int n_in,
                              void* d_out, int out_size, void* d_ws, size_t ws_size,
                              hipStream_t stream) {
  const float* X  = (const float*)d_in[0];
  const float* Y  = (const float*)d_in[1];
  const float* A1 = (const float*)d_in[2];
  const float* A2 = (const float*)d_in[3];
  float* C = (float*)d_out;

  const int B = 8, N = 2048, M = 2048, D = 128;

  unsigned short* Xn = (unsigned short*)d_ws;    // (B,N,128) bf16
  unsigned short* Yn = Xn + (size_t)B * N * D;   // (B,M,128) bf16

  const int rowsX = B * N, rowsY = B * M;
  gate_norm_kernel<<<dim3((rowsX + rowsY) / 8), dim3(256), 0, stream>>>(
      X, A1, Y, A2, Xn, Yn, rowsX);
  cosine_gemm_kernel<<<dim3(N / 128, M / 128, B), dim3(256), 0, stream>>>(Xn, Yn, C);
}

// Round 3
// 39.917 us; speedup vs baseline: 1.3185x; 1.3185x over previous
//
#include <hip/hip_runtime.h>
#include <hip/hip_bf16.h>

typedef __attribute__((ext_vector_type(8))) short bf16x8;   // 8 bf16 (4 VGPRs)
typedef __attribute__((ext_vector_type(4))) float f32x4;    // MFMA accumulator

#define CA_EPS 1e-6f

__device__ __forceinline__ unsigned short f2bf(float f) {
  // round-to-nearest-even bf16
  unsigned u = __float_as_uint(f);
  u += 0x7fffu + ((u >> 16) & 1u);
  return (unsigned short)(u >> 16);
}

// Gate + L2-normalize each 128-float row, emit bf16. One launch covers both
// X (blocks [0, rowsX/8)) and Y (blocks above) -- 8 rows per 256-thread block,
// so the X/Y split is block-uniform (no divergence).
__global__ void __launch_bounds__(256) gate_norm_kernel(
    const float* __restrict__ X, const float* __restrict__ A1,
    const float* __restrict__ Y, const float* __restrict__ A2,
    unsigned short* __restrict__ outX, unsigned short* __restrict__ outY,
    int rowsX) {
  int row = (int)((blockIdx.x * 256 + threadIdx.x) >> 5);
  int l = threadIdx.x & 31;
  const float* src;
  const float* gate;
  unsigned short* dst;
  if (row < rowsX) {
    src = X; gate = A1; dst = outX;
  } else {
    src = Y; gate = A2; dst = outY; row -= rowsX;
  }
  const float4 x = *(const float4*)(src + (size_t)row * 128 + l * 4);
  const float4 a = *(const float4*)(gate + (size_t)row * 128 + l * 4);
  float g0 = x.x * a.x, g1 = x.y * a.y, g2 = x.z * a.z, g3 = x.w * a.w;
  float ss = g0 * g0 + g1 * g1 + g2 * g2 + g3 * g3;
#pragma unroll
  for (int off = 16; off; off >>= 1) ss += __shfl_xor(ss, off);
  float inv = 1.0f / sqrtf(fmaxf(ss, CA_EPS));
  ushort4 o;
  o.x = f2bf(g0 * inv);
  o.y = f2bf(g1 * inv);
  o.z = f2bf(g2 * inv);
  o.w = f2bf(g3 * inv);
  *(ushort4*)(dst + (size_t)row * 128 + l * 4) = o;
}

#define GLOAD_LDS16(g, l)                                        \
  __builtin_amdgcn_global_load_lds(                              \
      (const __attribute__((address_space(1))) void*)(g),        \
      (__attribute__((address_space(3))) void*)(l), 16, 0, 0)

// C[b][n][m] = sum_k Xn[b][n][k] * Yn[b][m][k]  (bf16, row-major, K=128 whole row)
// 128x128 tile per block, 8 waves (2x4 wave grid, 64x32 per wave), 64 KB LDS,
// 2 blocks/CU -> 4 waves/SIMD for store/stage overlap.
// LDS XOR-swizzled (chunk ^= row&7) via pre-swizzled global source so the
// stride-256B ds_read_b128 fragment reads are bank-conflict-free (rule #21).
__global__ void __launch_bounds__(512, 4) cosine_gemm_kernel(
    const unsigned short* __restrict__ Xn,  // (B, 2048, 128) bf16
    const unsigned short* __restrict__ Yn,  // (B, 2048, 128) bf16
    float* __restrict__ C) {                // (B, 2048, 2048) f32
  __shared__ unsigned short ldsA[128 * 128];
  __shared__ unsigned short ldsB[128 * 128];

  const int tid = threadIdx.x;
  const int lane = tid & 63;
  const int w = tid >> 6;  // wave 0..7
  const int wr = w >> 2;   // wave row (0..1): 64-row slab of X tile
  const int wc = w & 3;    // wave col (0..3): 32-row slab of Y tile

  const int tn = blockIdx.x;
  const int tm = blockIdx.y;
  const int b = blockIdx.z;

  // Tiles span the full row dimension (d=128) -> contiguous 32 KB each.
  const unsigned short* Asrc = Xn + ((size_t)b * 2048 + (size_t)tn * 128) * 128;
  const unsigned short* Bsrc = Yn + ((size_t)b * 2048 + (size_t)tm * 128) * 128;

  // Stage 2048 16B-chunks per tile; 4 issues/thread/tile. LDS dest is linear
  // (wave-uniform base + lane*16); global source chunk is inverse-swizzled so
  // LDS chunk p holds global chunk (p ^ (row&7)).
#pragma unroll
  for (int i = 0; i < 4; ++i) {
    int p = i * 512 + tid;                             // linear dest chunk
    int q = (p & ~15) | ((p & 15) ^ ((p >> 4) & 7));   // swizzled source chunk
    GLOAD_LDS16(Asrc + (size_t)q * 8, &ldsA[(i * 512 + w * 64) * 8]);
    GLOAD_LDS16(Bsrc + (size_t)q * 8, &ldsB[(i * 512 + w * 64) * 8]);
  }
  __syncthreads();

  f32x4 acc[4][2] = {};
  const int r16 = lane & 15;  // frag row (A) / frag col (B,C)
  const int kq = lane >> 4;   // k-quarter 0..3

#pragma unroll
  for (int kk = 0; kk < 4; ++kk) {
    const int kc = kk * 4 + kq;  // 8-element K-chunk index (0..15)
    bf16x8 af[4], bfr[2];
#pragma unroll
    for (int mi = 0; mi < 4; ++mi) {
      int r = wr * 64 + mi * 16 + r16;
      af[mi] = *(const bf16x8*)(&ldsA[r * 128 + ((kc ^ (r & 7)) * 8)]);
    }
#pragma unroll
    for (int ni = 0; ni < 2; ++ni) {
      int r = wc * 32 + ni * 16 + r16;
      bfr[ni] = *(const bf16x8*)(&ldsB[r * 128 + ((kc ^ (r & 7)) * 8)]);
    }
#pragma unroll
    for (int mi = 0; mi < 4; ++mi)
#pragma unroll
      for (int ni = 0; ni < 2; ++ni)
        acc[mi][ni] = __builtin_amdgcn_mfma_f32_16x16x32_bf16(
            af[mi], bfr[ni], acc[mi][ni], 0, 0, 0);
  }

  // C/D layout (m89-verified): col = lane&15, row = (lane>>4)*4 + reg.
  float* Cb = C + ((size_t)b * 2048 + (size_t)tn * 128 + wr * 64) * 2048 +
              (size_t)tm * 128 + wc * 32;
#pragma unroll
  for (int mi = 0; mi < 4; ++mi) {
#pragma unroll
    for (int j = 0; j < 4; ++j) {
      float* crow = Cb + (size_t)(mi * 16 + kq * 4 + j) * 2048 + r16;
#pragma unroll
      for (int ni = 0; ni < 2; ++ni) crow[ni * 16] = acc[mi][ni][j];
    }
  }
}

extern "C" void kernel_launch(void* const* d_in, const int* in_sizes, int n_in,
                              void* d_out, int out_size, void* d_ws, size_t ws_size,
                              hipStream_t stream) {
  const float* X  = (const float*)d_in[0];
  const float* Y  = (const float*)d_in[1];
  const float* A1 = (const float*)d_in[2];
  const float* A2 = (const float*)d_in[3];
  float* C = (float*)d_out;

  const int B = 8, N = 2048, M = 2048, D = 128;

  unsigned short* Xn = (unsigned short*)d_ws;    // (B,N,128) bf16
  unsigned short* Yn = Xn + (size_t)B * N * D;   // (B,M,128) bf16

  const int rowsX = B * N, rowsY = B * M;
  gate_norm_kernel<<<dim3((rowsX + rowsY) / 8), dim3(256), 0, stream>>>(
      X, A1, Y, A2, Xn, Yn, rowsX);
  cosine_gemm_kernel<<<dim3(N / 128, M / 128, B), dim3(512), 0, stream>>>(Xn, Yn, C);
}

// Round 4
// 39.695 us; speedup vs baseline: 1.3259x; 1.0056x over previous
//
#include <hip/hip_runtime.h>
#include <hip/hip_bf16.h>

typedef __attribute__((ext_vector_type(8))) short bf16x8;   // 8 bf16 (4 VGPRs)
typedef __attribute__((ext_vector_type(4))) float f32x4;    // MFMA accumulator

#define CA_EPS 1e-6f

__device__ __forceinline__ unsigned short f2bf(float f) {
  // round-to-nearest-even bf16
  unsigned u = __float_as_uint(f);
  u += 0x7fffu + ((u >> 16) & 1u);
  return (unsigned short)(u >> 16);
}

// Gate + L2-normalize each 128-float row, emit bf16. One launch covers both
// X (blocks [0, rowsX/8)) and Y (blocks above) -- 8 rows per 256-thread block,
// so the X/Y split is block-uniform (no divergence).
__global__ void __launch_bounds__(256) gate_norm_kernel(
    const float* __restrict__ X, const float* __restrict__ A1,
    const float* __restrict__ Y, const float* __restrict__ A2,
    unsigned short* __restrict__ outX, unsigned short* __restrict__ outY,
    int rowsX) {
  int row = (int)((blockIdx.x * 256 + threadIdx.x) >> 5);
  int l = threadIdx.x & 31;
  const float* src;
  const float* gate;
  unsigned short* dst;
  if (row < rowsX) {
    src = X; gate = A1; dst = outX;
  } else {
    src = Y; gate = A2; dst = outY; row -= rowsX;
  }
  const float4 x = *(const float4*)(src + (size_t)row * 128 + l * 4);
  const float4 a = *(const float4*)(gate + (size_t)row * 128 + l * 4);
  float g0 = x.x * a.x, g1 = x.y * a.y, g2 = x.z * a.z, g3 = x.w * a.w;
  float ss = g0 * g0 + g1 * g1 + g2 * g2 + g3 * g3;
#pragma unroll
  for (int off = 16; off; off >>= 1) ss += __shfl_xor(ss, off);
  float inv = 1.0f / sqrtf(fmaxf(ss, CA_EPS));
  ushort4 o;
  o.x = f2bf(g0 * inv);
  o.y = f2bf(g1 * inv);
  o.z = f2bf(g2 * inv);
  o.w = f2bf(g3 * inv);
  *(ushort4*)(dst + (size_t)row * 128 + l * 4) = o;
}

#define GLOAD_LDS16(g, l)                                        \
  __builtin_amdgcn_global_load_lds(                              \
      (const __attribute__((address_space(1))) void*)(g),        \
      (__attribute__((address_space(3))) void*)(l), 16, 0, 0)

// C[b][n][m] = sum_k Xn[b][n][k] * Yn[b][m][k]  (bf16, row-major, K=128 whole row)
// WIDE output tile: 64 rows x 256 cols per block -> each C row gets a 1 KB
// contiguous run (DRAM page locality for the store stream, which dominates
// HBM traffic). 8 waves (1x8 wave grid, 64x32 slab each), LDS 80 KB
// (A 16 KB + B 64 KB) -> 2 blocks/CU.
// LDS XOR-swizzled (chunk ^= row&7) via pre-swizzled global source so the
// stride-256B ds_read_b128 fragment reads are bank-conflict-free (rule #21).
__global__ void __launch_bounds__(512, 4) cosine_gemm_kernel(
    const unsigned short* __restrict__ Xn,  // (B, 2048, 128) bf16
    const unsigned short* __restrict__ Yn,  // (B, 2048, 128) bf16
    float* __restrict__ C) {                // (B, 2048, 2048) f32
  __shared__ unsigned short ldsA[64 * 128];    // 16 KB
  __shared__ unsigned short ldsB[256 * 128];   // 64 KB

  const int tid = threadIdx.x;
  const int lane = tid & 63;
  const int w = tid >> 6;  // wave 0..7 = column slab (32 cols each)

  const int tn = blockIdx.x;  // 64-row slab of X / C rows (32 tiles)
  const int tm = blockIdx.y;  // 256-col slab of Y / C cols (8 tiles)
  const int b = blockIdx.z;

  // Tiles span the full row dimension (d=128) -> contiguous global blocks.
  const unsigned short* Asrc = Xn + ((size_t)b * 2048 + (size_t)tn * 64) * 128;
  const unsigned short* Bsrc = Yn + ((size_t)b * 2048 + (size_t)tm * 256) * 128;

  // Stage A: 1024 16B-chunks (2/thread); B: 4096 chunks (8/thread).
  // LDS dest linear (wave-uniform base + lane*16); global source chunk is
  // inverse-swizzled so LDS chunk p holds global chunk (p ^ (row&7)).
#pragma unroll
  for (int i = 0; i < 2; ++i) {
    int p = i * 512 + tid;
    int q = (p & ~15) | ((p & 15) ^ ((p >> 4) & 7));
    GLOAD_LDS16(Asrc + (size_t)q * 8, &ldsA[(i * 512 + w * 64) * 8]);
  }
#pragma unroll
  for (int i = 0; i < 8; ++i) {
    int p = i * 512 + tid;
    int q = (p & ~15) | ((p & 15) ^ ((p >> 4) & 7));
    GLOAD_LDS16(Bsrc + (size_t)q * 8, &ldsB[(i * 512 + w * 64) * 8]);
  }
  __syncthreads();

  f32x4 acc[4][2] = {};
  const int r16 = lane & 15;  // frag row (A) / frag col (B,C)
  const int kq = lane >> 4;   // k-quarter 0..3

#pragma unroll
  for (int kk = 0; kk < 4; ++kk) {
    const int kc = kk * 4 + kq;  // 8-element K-chunk index (0..15)
    bf16x8 af[4], bfr[2];
#pragma unroll
    for (int mi = 0; mi < 4; ++mi) {
      int r = mi * 16 + r16;  // A row 0..63
      af[mi] = *(const bf16x8*)(&ldsA[r * 128 + ((kc ^ (r & 7)) * 8)]);
    }
#pragma unroll
    for (int ni = 0; ni < 2; ++ni) {
      int r = w * 32 + ni * 16 + r16;  // B row 0..255
      bfr[ni] = *(const bf16x8*)(&ldsB[r * 128 + ((kc ^ (r & 7)) * 8)]);
    }
#pragma unroll
    for (int mi = 0; mi < 4; ++mi)
#pragma unroll
      for (int ni = 0; ni < 2; ++ni)
        acc[mi][ni] = __builtin_amdgcn_mfma_f32_16x16x32_bf16(
            af[mi], bfr[ni], acc[mi][ni], 0, 0, 0);
  }

  // C/D layout (m89-verified): col = lane&15, row = (lane>>4)*4 + reg.
  float* Cb = C + ((size_t)b * 2048 + (size_t)tn * 64) * 2048 +
              (size_t)tm * 256 + w * 32;
#pragma unroll
  for (int mi = 0; mi < 4; ++mi) {
#pragma unroll
    for (int j = 0; j < 4; ++j) {
      float* crow = Cb + (size_t)(mi * 16 + kq * 4 + j) * 2048 + r16;
#pragma unroll
      for (int ni = 0; ni < 2; ++ni) crow[ni * 16] = acc[mi][ni][j];
    }
  }
}

extern "C" void kernel_launch(void* const* d_in, const int* in_sizes, int n_in,
                              void* d_out, int out_size, void* d_ws, size_t ws_size,
                              hipStream_t stream) {
  const float* X  = (const float*)d_in[0];
  const float* Y  = (const float*)d_in[1];
  const float* A1 = (const float*)d_in[2];
  const float* A2 = (const float*)d_in[3];
  float* C = (float*)d_out;

  const int B = 8, N = 2048, M = 2048, D = 128;

  unsigned short* Xn = (unsigned short*)d_ws;    // (B,N,128) bf16
  unsigned short* Yn = Xn + (size_t)B * N * D;   // (B,M,128) bf16

  const int rowsX = B * N, rowsY = B * M;
  gate_norm_kernel<<<dim3((rowsX + rowsY) / 8), dim3(256), 0, stream>>>(
      X, A1, Y, A2, Xn, Yn, rowsX);
  cosine_gemm_kernel<<<dim3(N / 64, M / 256, B), dim3(512), 0, stream>>>(Xn, Yn, C);
}